// Round 6
// baseline (48.413 us; speedup 1.0000x reference)
//
#include <hip/hip_runtime.h>
#include <hip/hip_bf16.h>

#define IN_FEATS 64
#define OUT_FEATS 64
#define K_NEIGH 7
#define KDIM (K_NEIGH * IN_FEATS)   // 448

typedef __bf16 bf16x8 __attribute__((ext_vector_type(8)));
typedef float  f32x4  __attribute__((ext_vector_type(4)));

__device__ __forceinline__ unsigned short f2bf(float f) {
    union { float f; unsigned int u; } v; v.f = f;
    unsigned int u = v.u;
    unsigned int r = (u + 0x7FFFu + ((u >> 16) & 1u)) >> 16;   // RNE
    return (unsigned short)r;
}

__device__ __forceinline__ void gld_lds16(const void* gsrc, void* lds) {
    __builtin_amdgcn_global_load_lds(
        (const __attribute__((address_space(1))) void*)gsrc,
        (__attribute__((address_space(3))) void*)lds, 16, 0, 0);
}

// ---- kernel 1: cast x AND W fp32 -> bf16 (row layouts unchanged) ----
__global__ __launch_bounds__(256)
void cast_bf16_all(const float* __restrict__ x, const float* __restrict__ W,
                   __bf16* __restrict__ xb, __bf16* __restrict__ Wb,
                   int nx8, int nw8) {
    int i = blockIdx.x * 256 + threadIdx.x;
    const int stride = gridDim.x * 256;
    const int tot = nx8 + nw8;
    for (; i < tot; i += stride) {
        const float* s; __bf16* d; long j;
        if (i < nx8) { s = x; d = xb; j = i; }
        else         { s = W; d = Wb; j = i - nx8; }
        f32x4 a0 = *(const f32x4*)(s + j * 8);
        f32x4 a1 = *(const f32x4*)(s + j * 8 + 4);
        bf16x8 o;
        o[0] = (__bf16)a0.x; o[1] = (__bf16)a0.y; o[2] = (__bf16)a0.z; o[3] = (__bf16)a0.w;
        o[4] = (__bf16)a1.x; o[5] = (__bf16)a1.y; o[6] = (__bf16)a1.z; o[7] = (__bf16)a1.w;
        *(bf16x8*)(d + j * 8) = o;
    }
}

// ---- kernel 2: barrier-free per-wave gather pipelines ----
// 512 threads = 8 waves; wave owns 32 rows x 64 cols; 256 rows/block.
// W staged ONCE (57 KB swizzled); per-wave depth-3 A pipeline via
// global_load_lds + counted vmcnt; NO barriers inside the kn-loop.
// LDS = 57344 + 8*3*4096 = 155648 B -> 1 block/CU, 8 waves.
__global__ __launch_bounds__(512, 1)
void onering_glds2(const __bf16* __restrict__ xb,
                   const __bf16* __restrict__ Wb,
                   const int*   __restrict__ neigh,
                   const float* __restrict__ b,
                   float* __restrict__ out,
                   int n)
{
    __shared__ unsigned short wlds[OUT_FEATS * KDIM];   // 57344 B, XOR-swizzled
    __shared__ unsigned short lds_a[8][3][2048];        // per-wave triple buffer, 96 KB

    const int tid  = threadIdx.x;
    const int w    = tid >> 6;            // 0..7
    const int lane = tid & 63;
    const int lhi  = lane >> 4;           // 0..3
    const int llo  = lane & 15;           // 0..15

    const int rowbase = blockIdx.x * 256 + w * 32;

    // ---- neighbor indices ----
    int nidx[2][K_NEIGH];
    #pragma unroll
    for (int rt = 0; rt < 2; ++rt) {
        int r  = rowbase + rt * 16 + llo;
        int rr = (r < n) ? r : 0;
        #pragma unroll
        for (int kn = 0; kn < K_NEIGH; ++kn)
            nidx[rt][kn] = neigh[(long)rr * K_NEIGH + kn];
    }

    // ---- stage full W once: [64][448] bf16, byte ^= ((row&7)<<4) ----
    // 3584 16B-chunks; 512 threads x 7 chunks.
    #pragma unroll
    for (int q = 0; q < 7; ++q) {
        const int c = tid + q * 512;      // 0..3583
        const int e = c * 8;
        const int o = e / KDIM;
        const int k = e % KDIM;           // multiple of 8 -> dest 16B-aligned
        bf16x8 v = *(const bf16x8*)(Wb + e);
        const int dest = (o * (KDIM * 2) + k * 2) ^ ((o & 7) << 4);
        *(bf16x8*)((char*)wlds + dest) = v;
    }
    __syncthreads();                      // W visible; also drains prologue vmem

    const int aoff0 = lhi * 8;            // h=0 feats (bytes 0..63 of row)
    const int aoff1 = lhi * 8 + 32;       // h=1 feats (bytes 64..127)

    // 4 fire-and-forget gathers per phase per wave (A only; W already staged)
    #define ISSUE(kn_, p_) do {                                                   \
        gld_lds16(xb + (((long)nidx[0][kn_]) << 6) + aoff0, &lds_a[w][p_][0]);    \
        gld_lds16(xb + (((long)nidx[0][kn_]) << 6) + aoff1, &lds_a[w][p_][512]);  \
        gld_lds16(xb + (((long)nidx[1][kn_]) << 6) + aoff0, &lds_a[w][p_][1024]); \
        gld_lds16(xb + (((long)nidx[1][kn_]) << 6) + aoff1, &lds_a[w][p_][1536]); \
    } while (0)

    // ---- prologue: fill all three pipeline stages ----
    ISSUE(0, 0);
    ISSUE(1, 1);
    ISSUE(2, 2);

    f32x4 acc[2][4] = {};

    #pragma unroll
    for (int kn = 0; kn < K_NEIGH; ++kn) {
        const int p = kn % 3;

        // wait for group kn (oldest); kn+1/kn+2's 8 loads may stay in flight
        if (kn <= 4)      asm volatile("s_waitcnt vmcnt(8)" ::: "memory");
        else if (kn == 5) asm volatile("s_waitcnt vmcnt(4)" ::: "memory");
        else              asm volatile("s_waitcnt vmcnt(0)" ::: "memory");
        __builtin_amdgcn_sched_barrier(0);

        // ---- LDS -> registers ----
        bf16x8 af[2][2];
        #pragma unroll
        for (int rt = 0; rt < 2; ++rt)
            #pragma unroll
            for (int h = 0; h < 2; ++h)
                af[rt][h] = *(const bf16x8*)((const char*)&lds_a[w][p][rt * 1024 + h * 512]
                                             + lane * 16);
        bf16x8 bf[2][4];
        #pragma unroll
        for (int h = 0; h < 2; ++h)
            #pragma unroll
            for (int ct = 0; ct < 4; ++ct) {
                const int ocol    = ct * 16 + llo;
                const int klocal  = kn * 64 + h * 32 + lhi * 8;
                const int byteoff = (ocol * (KDIM * 2) + klocal * 2) ^ ((ocol & 7) << 4);
                bf[h][ct] = *(const bf16x8*)((const char*)wlds + byteoff);
            }

        // af/bf now in regs; safe to overwrite buffer p (rule #18 fence)
        asm volatile("s_waitcnt lgkmcnt(0)" ::: "memory");
        __builtin_amdgcn_sched_barrier(0);

        // refill buffer p for kn+3; overlaps this phase's MFMAs + 2 more phases
        if (kn == 0) ISSUE(3, 0);
        if (kn == 1) ISSUE(4, 1);
        if (kn == 2) ISSUE(5, 2);
        if (kn == 3) ISSUE(6, 0);

        #pragma unroll
        for (int h = 0; h < 2; ++h)
            #pragma unroll
            for (int ct = 0; ct < 4; ++ct)
                #pragma unroll
                for (int rt = 0; rt < 2; ++rt)
                    acc[rt][ct] = __builtin_amdgcn_mfma_f32_16x16x32_bf16(
                                      af[rt][h], bf[h][ct], acc[rt][ct], 0, 0, 0);
    }
    #undef ISSUE

    // ---- epilogue: bias + guarded store (C/D: col = lane&15, row = (lane>>4)*4 + reg) ----
    #pragma unroll
    for (int ct = 0; ct < 4; ++ct) {
        float bias = b[ct * 16 + llo];
        #pragma unroll
        for (int rt = 0; rt < 2; ++rt)
            #pragma unroll
            for (int j = 0; j < 4; ++j)
                acc[rt][ct][j] += bias;
    }
    #pragma unroll
    for (int rt = 0; rt < 2; ++rt) {
        const int rbase = rowbase + rt * 16 + lhi * 4;
        #pragma unroll
        for (int j = 0; j < 4; ++j) {
            const int r = rbase + j;
            if (r < n) {
                #pragma unroll
                for (int ct = 0; ct < 4; ++ct)
                    out[(long)r * OUT_FEATS + ct * 16 + llo] = acc[rt][ct][j];
            }
        }
    }
}

// ---- fallback (no workspace): fp32 gathers, self-contained ----
__global__ __launch_bounds__(512, 4)
void onering_mfma_f32(const float* __restrict__ x,
                      const int*   __restrict__ neigh,
                      const float* __restrict__ W,
                      const float* __restrict__ b,
                      float* __restrict__ out,
                      int n)
{
    __shared__ unsigned short wlds[OUT_FEATS * KDIM];
    const int tid  = threadIdx.x;
    const int wid  = tid >> 6;
    const int lane = tid & 63;
    const int lhi  = lane >> 4;
    const int llo  = lane & 15;

    for (int i = tid; i < (OUT_FEATS * KDIM) / 4; i += 512) {
        f32x4 w4 = *(const f32x4*)(W + i * 4);
        int e   = i * 4;
        int row = e / KDIM;
        ushort4 h;
        h.x = f2bf(w4.x); h.y = f2bf(w4.y); h.z = f2bf(w4.z); h.w = f2bf(w4.w);
        int byteoff = e * 2;
        byteoff ^= ((row & 7) << 4);
        *(ushort4*)((char*)wlds + byteoff) = h;
    }
    __syncthreads();

    const int rowbase = (blockIdx.x * 8 + wid) * 32;
    int nidx[2][K_NEIGH];
    #pragma unroll
    for (int rt = 0; rt < 2; ++rt) {
        int r  = rowbase + rt * 16 + llo;
        int rr = (r < n) ? r : 0;
        #pragma unroll
        for (int kn = 0; kn < K_NEIGH; ++kn)
            nidx[rt][kn] = neigh[(long)rr * K_NEIGH + kn];
    }

    f32x4 acc[2][4] = {};
    #pragma unroll
    for (int kn = 0; kn < K_NEIGH; ++kn) {
        bf16x8 afr[2][2];
        #pragma unroll
        for (int rt = 0; rt < 2; ++rt) {
            const float* xp = x + (long)nidx[rt][kn] * IN_FEATS + lhi * 8;
            #pragma unroll
            for (int h = 0; h < 2; ++h) {
                f32x4 a0 = *(const f32x4*)(xp + h * 32);
                f32x4 a1 = *(const f32x4*)(xp + h * 32 + 4);
                bf16x8 a;
                a[0] = (__bf16)a0.x; a[1] = (__bf16)a0.y;
                a[2] = (__bf16)a0.z; a[3] = (__bf16)a0.w;
                a[4] = (__bf16)a1.x; a[5] = (__bf16)a1.y;
                a[6] = (__bf16)a1.z; a[7] = (__bf16)a1.w;
                afr[rt][h] = a;
            }
        }
        #pragma unroll
        for (int h = 0; h < 2; ++h) {
            const int kk = kn * 2 + h;
            const int klocal = kk * 32 + lhi * 8;
            bf16x8 bfrag[4];
            #pragma unroll
            for (int ct = 0; ct < 4; ++ct) {
                int ocol    = ct * 16 + llo;
                int byteoff = ocol * (KDIM * 2) + klocal * 2;
                byteoff ^= ((ocol & 7) << 4);
                bfrag[ct] = *(const bf16x8*)((const char*)wlds + byteoff);
            }
            #pragma unroll
            for (int ct = 0; ct < 4; ++ct)
                #pragma unroll
                for (int rt = 0; rt < 2; ++rt)
                    acc[rt][ct] = __builtin_amdgcn_mfma_f32_16x16x32_bf16(
                                      afr[rt][h], bfrag[ct], acc[rt][ct], 0, 0, 0);
        }
    }

    #pragma unroll
    for (int ct = 0; ct < 4; ++ct) {
        float bias = b[ct * 16 + llo];
        #pragma unroll
        for (int rt = 0; rt < 2; ++rt)
            #pragma unroll
            for (int j = 0; j < 4; ++j)
                acc[rt][ct][j] += bias;
    }
    #pragma unroll
    for (int rt = 0; rt < 2; ++rt) {
        const int rbase = rowbase + rt * 16 + lhi * 4;
        #pragma unroll
        for (int j = 0; j < 4; ++j) {
            const int r = rbase + j;
            if (r < n) {
                #pragma unroll
                for (int ct = 0; ct < 4; ++ct)
                    out[(long)r * OUT_FEATS + ct * 16 + llo] = acc[rt][ct][j];
            }
        }
    }
}

extern "C" void kernel_launch(void* const* d_in, const int* in_sizes, int n_in,
                              void* d_out, int out_size, void* d_ws, size_t ws_size,
                              hipStream_t stream) {
    const float* x     = (const float*)d_in[0];
    const int*   neigh = (const int*)d_in[1];
    const float* W     = (const float*)d_in[2];
    const float* b     = (const float*)d_in[3];
    float* out = (float*)d_out;

    const int n = in_sizes[0] / IN_FEATS;              // 163842

    // ws layout: Wb bf16 [64][448] at offset 0 (57344 B, padded to 64 KB),
    //            xb bf16 [n][64]   at offset 65536.
    const size_t need = 65536 + (size_t)n * IN_FEATS * sizeof(unsigned short);
    if (ws_size >= need) {
        __bf16* Wb = (__bf16*)d_ws;
        __bf16* xb = (__bf16*)((char*)d_ws + 65536);
        const int nx8 = n * IN_FEATS / 8;
        const int nw8 = OUT_FEATS * KDIM / 8;          // 3584
        cast_bf16_all<<<dim3(2048), dim3(256), 0, stream>>>(x, W, xb, Wb, nx8, nw8);
        const int nblocks = (n + 255) / 256;           // 641
        onering_glds2<<<dim3(nblocks), dim3(512), 0, stream>>>(
            xb, Wb, neigh, b, out, n);
    } else {
        const int nblocks = (n + 255) / 256;
        onering_mfma_f32<<<dim3(nblocks), dim3(512), 0, stream>>>(
            x, neigh, W, b, out, n);
    }
}

// Round 7
// 43.475 us; speedup vs baseline: 1.1136x; 1.1136x over previous
//
#include <hip/hip_runtime.h>
#include <hip/hip_bf16.h>

#define IN_FEATS 64
#define OUT_FEATS 64
#define K_NEIGH 7
#define KDIM (K_NEIGH * IN_FEATS)   // 448

typedef __bf16 bf16x8 __attribute__((ext_vector_type(8)));
typedef float  f32x4  __attribute__((ext_vector_type(4)));

__device__ __forceinline__ unsigned short f2bf(float f) {
    union { float f; unsigned int u; } v; v.f = f;
    unsigned int u = v.u;
    unsigned int r = (u + 0x7FFFu + ((u >> 16) & 1u)) >> 16;   // RNE
    return (unsigned short)r;
}

__device__ __forceinline__ void gld_lds16(const void* gsrc, void* lds) {
    __builtin_amdgcn_global_load_lds(
        (const __attribute__((address_space(1))) void*)gsrc,
        (__attribute__((address_space(3))) void*)lds, 16, 0, 0);
}

// ---- kernel 1: cast x AND W fp32 -> bf16 (row layouts unchanged) ----
__global__ __launch_bounds__(256)
void cast_bf16_all(const float* __restrict__ x, const float* __restrict__ W,
                   __bf16* __restrict__ xb, __bf16* __restrict__ Wb,
                   int nx8, int nw8) {
    int i = blockIdx.x * 256 + threadIdx.x;
    const int stride = gridDim.x * 256;
    const int tot = nx8 + nw8;
    for (; i < tot; i += stride) {
        const float* s; __bf16* d; long j;
        if (i < nx8) { s = x; d = xb; j = i; }
        else         { s = W; d = Wb; j = i - nx8; }
        f32x4 a0 = *(const f32x4*)(s + j * 8);
        f32x4 a1 = *(const f32x4*)(s + j * 8 + 4);
        bf16x8 o;
        o[0] = (__bf16)a0.x; o[1] = (__bf16)a0.y; o[2] = (__bf16)a0.z; o[3] = (__bf16)a0.w;
        o[4] = (__bf16)a1.x; o[5] = (__bf16)a1.y; o[6] = (__bf16)a1.z; o[7] = (__bf16)a1.w;
        *(bf16x8*)(d + j * 8) = o;
    }
}

// ---- kernel 2: round-5 structure, FULL-ROW gather instructions ----
// 256 threads = 4 waves; wave owns 32 rows x 64 cols; 128 rows/block.
// Each glds instruction gathers 8 rows x 128 B (8 lanes/row) with intra-row
// chunk XOR pre-swizzle at the SOURCE (linear LDS dest, XOR on ds_read).
// LDS 48 KB -> 3 blocks/CU. Depth-2 phase pipeline over kn=0..6.
__global__ __launch_bounds__(256, 3)
void onering_glds3(const __bf16* __restrict__ xb,
                   const __bf16* __restrict__ Wb,
                   const int*   __restrict__ neigh,
                   const float* __restrict__ b,
                   float* __restrict__ out,
                   int n)
{
    // per-kn W slice [64 out][64 k] bf16, XOR-swizzled via pre-swizzled SOURCE
    __shared__ unsigned short lds_w[2][OUT_FEATS * 64];   // 2 x 8 KB
    // per-wave gathered A tile: 32 rows x 128 B (chunk-swizzled within row)
    __shared__ unsigned short lds_a[2][4][2048];          // 2 x 4 x 4 KB

    const int tid  = threadIdx.x;
    const int w    = tid >> 6;
    const int lane = tid & 63;
    const int lhi  = lane >> 4;           // 0..3
    const int llo  = lane & 15;           // 0..15

    const int rowbase = blockIdx.x * 128 + w * 32;

    // ---- neighbor indices keyed by this lane's GATHER role (lane>>3) ----
    // instr (rt,q) lane l handles output row rowbase + rt*16 + q*8 + (l>>3)
    const int lr8 = lane >> 3;            // 0..7
    int nidx2[2][2][K_NEIGH];
    #pragma unroll
    for (int rt = 0; rt < 2; ++rt)
        #pragma unroll
        for (int q = 0; q < 2; ++q) {
            int r  = rowbase + rt * 16 + q * 8 + lr8;
            int rr = (r < n) ? r : 0;
            #pragma unroll
            for (int kn = 0; kn < K_NEIGH; ++kn)
                nidx2[rt][q][kn] = neigh[(long)rr * K_NEIGH + kn];
        }

    // ---- W-gather lane constants (inverse of the read swizzle; as round 5) ----
    const int j0  = w * 2, j1 = w * 2 + 1;
    const int wo0 = j0 * 8 + lr8;
    const int wo1 = j1 * 8 + lr8;
    const int wc  = (((lane & 7) ^ (lr8 & 7)) * 8);
    const __bf16* wsrc0 = Wb + (long)wo0 * KDIM + wc;     // + kn*64 per phase
    const __bf16* wsrc1 = Wb + (long)wo1 * KDIM + wc;

    // ---- A-gather source chunk (intra-row XOR pre-swizzle) ----
    // lane l reads chunk (l&7)^(row&7) of its row; row&7 == lr8 (r0 % 8 == 0)
    const int csrc = ((lane & 7) ^ (lr8 & 7)) * 8;        // bf16 elems (16B chunks)

    // 6 fire-and-forget loads per phase per wave (4 full-row A-gathers + 2 W)
    #define ISSUE(kn_, p_) do {                                                     \
        gld_lds16(xb + (((long)nidx2[0][0][kn_]) << 6) + csrc, &lds_a[p_][w][0]);    \
        gld_lds16(xb + (((long)nidx2[0][1][kn_]) << 6) + csrc, &lds_a[p_][w][512]);  \
        gld_lds16(xb + (((long)nidx2[1][0][kn_]) << 6) + csrc, &lds_a[p_][w][1024]); \
        gld_lds16(xb + (((long)nidx2[1][1][kn_]) << 6) + csrc, &lds_a[p_][w][1536]); \
        gld_lds16(wsrc0 + (kn_) * 64, &lds_w[p_][j0 * 512]);                         \
        gld_lds16(wsrc1 + (kn_) * 64, &lds_w[p_][j1 * 512]);                         \
    } while (0)

    // ---- prologue: fill both pipeline stages ----
    ISSUE(0, 0);
    ISSUE(1, 1);

    f32x4 acc[2][4] = {};

    #pragma unroll
    for (int kn = 0; kn < K_NEIGH; ++kn) {
        const int p = kn & 1;

        // phase-kn loads are the oldest outstanding; kn+1's 6 may stay in flight
        if (kn < 6) asm volatile("s_waitcnt vmcnt(6)" ::: "memory");
        else        asm volatile("s_waitcnt vmcnt(0)" ::: "memory");
        __builtin_amdgcn_sched_barrier(0);
        __builtin_amdgcn_s_barrier();          // buffer p fully staged, all waves
        __builtin_amdgcn_sched_barrier(0);

        // ---- LDS -> registers ----
        // A tile: row-major [32][128B], chunk c of row r at slot c^(r&7)
        bf16x8 af[2][2];
        #pragma unroll
        for (int rt = 0; rt < 2; ++rt)
            #pragma unroll
            for (int h = 0; h < 2; ++h) {
                const int row  = rt * 16 + llo;
                const int slot = (h * 4 + lhi) ^ (llo & 7);
                af[rt][h] = *(const bf16x8*)((const char*)&lds_a[p][w][0]
                                             + row * 128 + slot * 16);
            }
        bf16x8 bf[2][4];
        #pragma unroll
        for (int h = 0; h < 2; ++h)
            #pragma unroll
            for (int ct = 0; ct < 4; ++ct) {
                const int ocol    = ct * 16 + llo;
                const int klocal  = h * 32 + lhi * 8;
                const int byteoff = (ocol * 128 + klocal * 2) ^ ((ocol & 7) << 4);
                bf[h][ct] = *(const bf16x8*)((const char*)&lds_w[p][0] + byteoff);
            }

        // all our LDS reads retired -> buffer p reusable once every wave agrees
        asm volatile("s_waitcnt lgkmcnt(0)" ::: "memory");
        __builtin_amdgcn_sched_barrier(0);
        __builtin_amdgcn_s_barrier();          // all waves done reading buffer p
        __builtin_amdgcn_sched_barrier(0);

        // refill buffer p for kn+2; loads overlap the MFMAs below and phase kn+1
        if (kn + 2 <= 6) {
            if (kn == 0) ISSUE(2, 0);
            if (kn == 1) ISSUE(3, 1);
            if (kn == 2) ISSUE(4, 0);
            if (kn == 3) ISSUE(5, 1);
            if (kn == 4) ISSUE(6, 0);
        }

        #pragma unroll
        for (int h = 0; h < 2; ++h)
            #pragma unroll
            for (int ct = 0; ct < 4; ++ct)
                #pragma unroll
                for (int rt = 0; rt < 2; ++rt)
                    acc[rt][ct] = __builtin_amdgcn_mfma_f32_16x16x32_bf16(
                                      af[rt][h], bf[h][ct], acc[rt][ct], 0, 0, 0);
    }
    #undef ISSUE

    // ---- epilogue: bias + guarded store (C/D: col = lane&15, row = (lane>>4)*4 + reg) ----
    #pragma unroll
    for (int ct = 0; ct < 4; ++ct) {
        float bias = b[ct * 16 + llo];
        #pragma unroll
        for (int rt = 0; rt < 2; ++rt)
            #pragma unroll
            for (int j = 0; j < 4; ++j)
                acc[rt][ct][j] += bias;
    }
    #pragma unroll
    for (int rt = 0; rt < 2; ++rt) {
        const int rbase = rowbase + rt * 16 + lhi * 4;
        #pragma unroll
        for (int j = 0; j < 4; ++j) {
            const int r = rbase + j;
            if (r < n) {
                #pragma unroll
                for (int ct = 0; ct < 4; ++ct)
                    out[(long)r * OUT_FEATS + ct * 16 + llo] = acc[rt][ct][j];
            }
        }
    }
}

// ---- fallback (no workspace): fp32 gathers, self-contained ----
__global__ __launch_bounds__(512, 4)
void onering_mfma_f32(const float* __restrict__ x,
                      const int*   __restrict__ neigh,
                      const float* __restrict__ W,
                      const float* __restrict__ b,
                      float* __restrict__ out,
                      int n)
{
    __shared__ unsigned short wlds[OUT_FEATS * KDIM];
    const int tid  = threadIdx.x;
    const int wid  = tid >> 6;
    const int lane = tid & 63;
    const int lhi  = lane >> 4;
    const int llo  = lane & 15;

    for (int i = tid; i < (OUT_FEATS * KDIM) / 4; i += 512) {
        f32x4 w4 = *(const f32x4*)(W + i * 4);
        int e   = i * 4;
        int row = e / KDIM;
        ushort4 h;
        h.x = f2bf(w4.x); h.y = f2bf(w4.y); h.z = f2bf(w4.z); h.w = f2bf(w4.w);
        int byteoff = e * 2;
        byteoff ^= ((row & 7) << 4);
        *(ushort4*)((char*)wlds + byteoff) = h;
    }
    __syncthreads();

    const int rowbase = (blockIdx.x * 8 + wid) * 32;
    int nidx[2][K_NEIGH];
    #pragma unroll
    for (int rt = 0; rt < 2; ++rt) {
        int r  = rowbase + rt * 16 + llo;
        int rr = (r < n) ? r : 0;
        #pragma unroll
        for (int kn = 0; kn < K_NEIGH; ++kn)
            nidx[rt][kn] = neigh[(long)rr * K_NEIGH + kn];
    }

    f32x4 acc[2][4] = {};
    #pragma unroll
    for (int kn = 0; kn < K_NEIGH; ++kn) {
        bf16x8 afr[2][2];
        #pragma unroll
        for (int rt = 0; rt < 2; ++rt) {
            const float* xp = x + (long)nidx[rt][kn] * IN_FEATS + lhi * 8;
            #pragma unroll
            for (int h = 0; h < 2; ++h) {
                f32x4 a0 = *(const f32x4*)(xp + h * 32);
                f32x4 a1 = *(const f32x4*)(xp + h * 32 + 4);
                bf16x8 a;
                a[0] = (__bf16)a0.x; a[1] = (__bf16)a0.y;
                a[2] = (__bf16)a0.z; a[3] = (__bf16)a0.w;
                a[4] = (__bf16)a1.x; a[5] = (__bf16)a1.y;
                a[6] = (__bf16)a1.z; a[7] = (__bf16)a1.w;
                afr[rt][h] = a;
            }
        }
        #pragma unroll
        for (int h = 0; h < 2; ++h) {
            const int kk = kn * 2 + h;
            const int klocal = kk * 32 + lhi * 8;
            bf16x8 bfrag[4];
            #pragma unroll
            for (int ct = 0; ct < 4; ++ct) {
                int ocol    = ct * 16 + llo;
                int byteoff = ocol * (KDIM * 2) + klocal * 2;
                byteoff ^= ((ocol & 7) << 4);
                bfrag[ct] = *(const bf16x8*)((const char*)wlds + byteoff);
            }
            #pragma unroll
            for (int ct = 0; ct < 4; ++ct)
                #pragma unroll
                for (int rt = 0; rt < 2; ++rt)
                    acc[rt][ct] = __builtin_amdgcn_mfma_f32_16x16x32_bf16(
                                      afr[rt][h], bfrag[ct], acc[rt][ct], 0, 0, 0);
        }
    }

    #pragma unroll
    for (int ct = 0; ct < 4; ++ct) {
        float bias = b[ct * 16 + llo];
        #pragma unroll
        for (int rt = 0; rt < 2; ++rt)
            #pragma unroll
            for (int j = 0; j < 4; ++j)
                acc[rt][ct][j] += bias;
    }
    #pragma unroll
    for (int rt = 0; rt < 2; ++rt) {
        const int rbase = rowbase + rt * 16 + lhi * 4;
        #pragma unroll
        for (int j = 0; j < 4; ++j) {
            const int r = rbase + j;
            if (r < n) {
                #pragma unroll
                for (int ct = 0; ct < 4; ++ct)
                    out[(long)r * OUT_FEATS + ct * 16 + llo] = acc[rt][ct][j];
            }
        }
    }
}

extern "C" void kernel_launch(void* const* d_in, const int* in_sizes, int n_in,
                              void* d_out, int out_size, void* d_ws, size_t ws_size,
                              hipStream_t stream) {
    const float* x     = (const float*)d_in[0];
    const int*   neigh = (const int*)d_in[1];
    const float* W     = (const float*)d_in[2];
    const float* b     = (const float*)d_in[3];
    float* out = (float*)d_out;

    const int n = in_sizes[0] / IN_FEATS;              // 163842

    // ws layout: Wb bf16 [64][448] at offset 0 (57344 B, padded to 64 KB),
    //            xb bf16 [n][64]   at offset 65536.
    const size_t need = 65536 + (size_t)n * IN_FEATS * sizeof(unsigned short);
    if (ws_size >= need) {
        __bf16* Wb = (__bf16*)d_ws;
        __bf16* xb = (__bf16*)((char*)d_ws + 65536);
        const int nx8 = n * IN_FEATS / 8;
        const int nw8 = OUT_FEATS * KDIM / 8;          // 3584
        cast_bf16_all<<<dim3(2048), dim3(256), 0, stream>>>(x, W, xb, Wb, nx8, nw8);
        const int nblocks = (n + 127) / 128;           // 1281
        onering_glds3<<<dim3(nblocks), dim3(256), 0, stream>>>(
            xb, Wb, neigh, b, out, n);
    } else {
        const int nblocks = (n + 255) / 256;
        onering_mfma_f32<<<dim3(nblocks), dim3(512), 0, stream>>>(
            x, neigh, W, b, out, n);
    }
}